// Round 6
// baseline (44.023 us; speedup 1.0000x reference)
//
#include <hip/hip_runtime.h>
#include <hip/hip_bf16.h>

#define HC 60
#define WCC 60
#define DD 64
#define NCELL (HC * WCC)      // 3600
#define NBC (4 * NCELL)       // 14400
#define IMG (HC * 8)          // 480
#define MPAD 3840             // 30 * 128 zero-padded rows per batch
#define NT2 30                // 128-tiles per dim
#define NTILES (NT2 * NT2 * 4)   // 3600
#define GB 768                // persistent gemm blocks (3/CU)

#define CVT_BLOCKS 480        // 4*3840*64/8 / 256
#define VM_BLOCKS 57          // ceil(14400/256)
#define WC_BLOCKS 60          // 4*3840/256
#define PREP_BLOCKS (CVT_BLOCKS + VM_BLOCKS + WC_BLOCKS)   // 597

typedef __bf16 bf16x8 __attribute__((ext_vector_type(8)));
typedef float f32x4 __attribute__((ext_vector_type(4)));
typedef unsigned short u16x8 __attribute__((ext_vector_type(8)));

__device__ inline unsigned short f2bf(float f) {
    union { float f; unsigned u; } x; x.f = f;
    unsigned u = x.u;
    unsigned r = (u + 0x7fffu + ((u >> 16) & 1u)) >> 16;  // RNE
    return (unsigned short)r;
}

__device__ inline void gload_lds16(const void* g, void* l) {
    __builtin_amdgcn_global_load_lds(
        (const __attribute__((address_space(1))) unsigned int*)g,
        (__attribute__((address_space(3))) unsigned int*)l, 16, 0, 0);
}

__device__ inline int div60(int v) { return (v * 17477) >> 20; }  // exact for 0<=v<3840

// ---- kernel 1 (fused prep): f32->bf16 convert (padded), vm + partial sum, warped centers ----
__global__ __launch_bounds__(256) void dl_prep_kernel(
    const float* __restrict__ desc, const float* __restrict__ wdesc,
    const float* __restrict__ homog, const float* __restrict__ mask,
    unsigned short* __restrict__ descb, unsigned short* __restrict__ wdescb,
    float* __restrict__ vm, float* __restrict__ vpart, float2* __restrict__ wcent,
    unsigned int* __restrict__ done)
{
    const int bid = blockIdx.x;
    const int tid = threadIdx.x;

    if (bid < CVT_BLOCKS) {
        int t = bid * 256 + tid;
        int brow = t >> 3;
        int col = (t & 7) * 8;
        int b = brow / MPAD;
        int row = brow - b * MPAD;
        u16x8 oa = (u16x8)0, ob = (u16x8)0;
        if (row < NCELL) {
            size_t src = ((size_t)(b * NCELL + row)) * DD + col;
            float4 a0 = *(const float4*)(desc + src);
            float4 a1 = *(const float4*)(desc + src + 4);
            float4 b0 = *(const float4*)(wdesc + src);
            float4 b1 = *(const float4*)(wdesc + src + 4);
            oa[0] = f2bf(a0.x); oa[1] = f2bf(a0.y); oa[2] = f2bf(a0.z); oa[3] = f2bf(a0.w);
            oa[4] = f2bf(a1.x); oa[5] = f2bf(a1.y); oa[6] = f2bf(a1.z); oa[7] = f2bf(a1.w);
            ob[0] = f2bf(b0.x); ob[1] = f2bf(b0.y); ob[2] = f2bf(b0.z); ob[3] = f2bf(b0.w);
            ob[4] = f2bf(b1.x); ob[5] = f2bf(b1.y); ob[6] = f2bf(b1.z); ob[7] = f2bf(b1.w);
        }
        size_t dst = (size_t)brow * DD + col;
        *(u16x8*)(descb + dst) = oa;
        *(u16x8*)(wdescb + dst) = ob;
    } else if (bid < CVT_BLOCKS + VM_BLOCKS) {
        int vb = bid - CVT_BLOCKS;
        int cell = vb * 256 + tid;
        float v = 0.f;
        if (cell < NBC) {
            int b = cell / NCELL;
            int rem = cell % NCELL;
            int k = rem / WCC, l = rem % WCC;
            const float* p = mask + (size_t)b * IMG * IMG + (size_t)(k * 8) * IMG + l * 8;
            float prod = 1.f;
#pragma unroll
            for (int dy = 0; dy < 8; ++dy) {
                float4 a0 = *(const float4*)(p + (size_t)dy * IMG);
                float4 a1 = *(const float4*)(p + (size_t)dy * IMG + 4);
                prod *= a0.x * a0.y * a0.z * a0.w * a1.x * a1.y * a1.z * a1.w;
            }
            vm[cell] = prod;
            v = prod;
        }
#pragma unroll
        for (int off = 32; off > 0; off >>= 1) v += __shfl_xor(v, off);
        __shared__ float sp[4];
        if ((tid & 63) == 0) sp[tid >> 6] = v;
        __syncthreads();
        if (tid == 0) vpart[vb] = sp[0] + sp[1] + sp[2] + sp[3];
    } else {
        if (bid == CVT_BLOCKS + VM_BLOCKS && tid == 0) *done = 0u;  // reset finale counter
        int t = (bid - CVT_BLOCKS - VM_BLOCKS) * 256 + tid;   // 0 .. 15359
        int b = t / MPAD;
        int r = t - b * MPAD;
        float2 o;
        if (r < NCELL) {
            int i = div60(r);
            int j = r - i * WCC;
            const float* H = homog + b * 9;
            float x = (float)(j * 8 + 4), y = (float)(i * 8 + 4);
            float X2 = H[6] * x + H[7] * y + H[8];
            o.x = (H[3] * x + H[4] * y + H[5]) / X2;   // wy
            o.y = (H[0] * x + H[1] * y + H[2]) / X2;   // wx
        } else {
            o.x = 1e9f; o.y = 1e9f;                    // pad rows: s = 0, simple path
        }
        wcent[t] = o;
    }
}

// ---- kernel 2: persistent 128x128-tile GEMM, A-reuse, B double-buffer, fused finale ----
__global__ __launch_bounds__(256, 3) void dl_gemm_loss_kernel(
    const unsigned short* __restrict__ descb, const unsigned short* __restrict__ wdescb,
    const float* __restrict__ vm, const float2* __restrict__ wcent,
    const float* __restrict__ vpart,
    float* __restrict__ gpart, unsigned int* __restrict__ done,
    float* __restrict__ out)
{
    __shared__ unsigned char sA[16384];        // A tile: 128 rows x 128B, swizzled
    __shared__ unsigned char sB[2][16384];     // B tiles, double-buffered
    __shared__ float2 swc[128];
    __shared__ float sred[8];
    __shared__ unsigned int slast;

    const int tid = threadIdx.x;
    const int lane = tid & 63;
    const int wv = tid >> 6;                   // 0..3
    const int p = blockIdx.x;
    const int t0 = (NTILES * p) / GB;
    const int t1 = (NTILES * (p + 1)) / GB;

    const int wr = wv >> 1, wcs = wv & 1;      // wave -> 64x64 subtile
    const int frow = lane & 15;
    const int kg = (lane >> 4) * 16;
    const int swz = ((lane & 7) ^ (lane >> 3)) << 4;
    const int lrow = lane >> 3;

    float partial = 0.f;
    float wlo = 0.f, whi = 0.f;
    int pb = 0;
    int curax = -1;

    for (int t = t0; t < t1; ++t) {
        int b = t / (NT2 * NT2);
        int r = t - b * (NT2 * NT2);
        int x = r / NT2;
        int y = r - x * NT2;
        int axkey = b * 32 + x;

        if (axkey != curax) {
            // cold start for a new A-tile: stage A + swc + B(t), then drain
            const unsigned char* gA = (const unsigned char*)(descb + (size_t)b * MPAD * DD)
                                      + (size_t)(x * 128) * 128;
            const unsigned char* gB = (const unsigned char*)(wdescb + (size_t)b * MPAD * DD)
                                      + (size_t)(y * 128) * 128;
#pragma unroll
            for (int q = 0; q < 4; ++q) {
                int row = wv * 32 + q * 8 + lrow;
                gload_lds16(gA + (size_t)row * 128 + swz, sA + wv * 4096 + q * 1024);
                gload_lds16(gB + (size_t)row * 128 + swz, sB[pb] + wv * 4096 + q * 1024);
            }
            if (tid < 128) swc[tid] = wcent[b * MPAD + x * 128 + tid];
            float wyl = wcent[b * MPAD + x * 128 + wr * 64 + lane].x;
            wlo = wyl; whi = wyl;
#pragma unroll
            for (int off = 32; off > 0; off >>= 1) {
                wlo = fminf(wlo, __shfl_xor(wlo, off));
                whi = fmaxf(whi, __shfl_xor(whi, off));
            }
            curax = axkey;
            __syncthreads();
        }

        // prefetch next tile's B while computing this one (shares A by construction)
        bool pref = false;
        {
            int tn = t + 1;
            if (tn < t1) {
                int bn = tn / (NT2 * NT2);
                int rn = tn - bn * (NT2 * NT2);
                int xn = rn / NT2;
                int yn = rn - xn * NT2;
                if (bn * 32 + xn == curax) {
                    const unsigned char* gBn =
                        (const unsigned char*)(wdescb + (size_t)bn * MPAD * DD)
                        + (size_t)(yn * 128) * 128;
#pragma unroll
                    for (int q = 0; q < 4; ++q) {
                        int row = wv * 32 + q * 8 + lrow;
                        gload_lds16(gBn + (size_t)row * 128 + swz,
                                    sB[pb ^ 1] + wv * 4096 + q * 1024);
                    }
                    pref = true;
                }
            }
        }

        // col geometry + vm for this tile (independent of LDS -> overlaps loads)
        int n0 = y * 128;
        float cyv[4], cxv[4], vmv[4];
#pragma unroll
        for (int fj = 0; fj < 4; ++fj) {
            int col = n0 + wcs * 64 + fj * 16 + frow;
            int k = div60(col);
            int l = col - k * WCC;
            cyv[fj] = (float)(k * 8 + 4);
            cxv[fj] = (float)(l * 8 + 4);
            vmv[fj] = (col < NCELL) ? vm[b * NCELL + col] : 0.f;
        }
        int c0 = n0 + wcs * 64;
        float cy0 = (float)(div60(c0) * 8 + 4) - 7.5f;
        float cy1 = (float)(div60(c0 + 63) * 8 + 4) + 7.5f;
        bool full = (whi >= cy0) && (wlo <= cy1);

        f32x4 acc[4][4];
#pragma unroll
        for (int i2 = 0; i2 < 4; ++i2)
#pragma unroll
            for (int j2 = 0; j2 < 4; ++j2)
                acc[i2][j2] = (f32x4)(0.f);

        const unsigned char* bB = sB[pb];
#pragma unroll
        for (int kk = 0; kk < 2; ++kk) {
            int kbyte = kk * 64 + kg;
            bf16x8 afr[4], bfr[4];
#pragma unroll
            for (int f = 0; f < 4; ++f) {
                int ra = wr * 64 + f * 16 + frow;
                afr[f] = *(const bf16x8*)(sA + ra * 128 + (kbyte ^ ((ra & 7) << 4)));
                int rb = wcs * 64 + f * 16 + frow;
                bfr[f] = *(const bf16x8*)(bB + rb * 128 + (kbyte ^ ((rb & 7) << 4)));
            }
#pragma unroll
            for (int fi = 0; fi < 4; ++fi)
#pragma unroll
                for (int fj = 0; fj < 4; ++fj)
                    acc[fi][fj] = __builtin_amdgcn_mfma_f32_16x16x32_bf16(
                        afr[fi], bfr[fj], acc[fi][fj], 0, 0, 0);
        }

        // max-form epilogue: vm*max(dot,0.2); s=1 -> vm*(250*relu(1-dot)+0.2)
        if (full) {
#pragma unroll
            for (int fi = 0; fi < 4; ++fi) {
#pragma unroll
                for (int q = 0; q < 4; ++q) {
                    float2 w2 = swc[wr * 64 + fi * 16 + (lane >> 4) * 4 + q];
#pragma unroll
                    for (int fj = 0; fj < 4; ++fj) {
                        float dot = acc[fi][fj][q];
                        float ddy = cyv[fj] - w2.x;
                        float ddx = cxv[fj] - w2.y;
                        float d2 = ddy * ddy + ddx * ddx;
                        float pos = 250.f * fmaxf(1.f - dot, 0.f) + 0.2f;
                        float neg = fmaxf(dot, 0.2f);
                        partial += vmv[fj] * ((d2 <= 56.25f) ? pos : neg);
                    }
                }
            }
        } else {
#pragma unroll
            for (int fj = 0; fj < 4; ++fj) {
                float cs = 0.f;
#pragma unroll
                for (int fi = 0; fi < 4; ++fi)
#pragma unroll
                    for (int q = 0; q < 4; ++q)
                        cs += fmaxf(acc[fi][fj][q], 0.2f);
                partial = fmaf(vmv[fj], cs, partial);
            }
        }

        __syncthreads();          // drains prefetched B(t+1); next iter may overwrite sB[pb]
        if (pref) pb ^= 1;
    }

    // block reduction -> gpart[p]; last finished block computes the scalar
#pragma unroll
    for (int off = 32; off > 0; off >>= 1) partial += __shfl_xor(partial, off);
    if (lane == 0) sred[wv] = partial;
    __syncthreads();
    if (tid == 0) {
        gpart[p] = sred[0] + sred[1] + sred[2] + sred[3];
        __threadfence();
        slast = atomicAdd(done, 1u);
    }
    __syncthreads();
    if (slast == GB - 1) {
        __threadfence();
        float ls = 0.f, vs = 0.f;
        for (int i = tid; i < GB; i += 256) ls += gpart[i];
        for (int i = tid; i < VM_BLOCKS; i += 256) vs += vpart[i];
#pragma unroll
        for (int off = 32; off > 0; off >>= 1) {
            ls += __shfl_xor(ls, off);
            vs += __shfl_xor(vs, off);
        }
        __shared__ float sl[4], sv[4];
        if ((tid & 63) == 0) { sl[tid >> 6] = ls; sv[tid >> 6] = vs; }
        __syncthreads();
        if (tid == 0) {
            float L = sl[0] + sl[1] + sl[2] + sl[3];
            float V = sv[0] + sv[1] + sv[2] + sv[3];
            L -= 0.2f * (float)MPAD * V;      // max-form global correction
            out[0] = L / (V * (float)NCELL);
        }
    }
}

extern "C" void kernel_launch(void* const* d_in, const int* in_sizes, int n_in,
                              void* d_out, int out_size, void* d_ws, size_t ws_size,
                              hipStream_t stream) {
    const float* desc  = (const float*)d_in[0];
    const float* wdesc = (const float*)d_in[1];
    const float* homog = (const float*)d_in[2];
    const float* mask  = (const float*)d_in[3];
    float* out = (float*)d_out;
    float* wsf = (float*)d_ws;

    // workspace layout (floats); every slot fully overwritten (or zeroed by prep) each call
    float* vpart = wsf;                           // [57]
    float* vm    = wsf + 64;                      // [14400]
    float* gpart = wsf + 64 + NBC;                // [768] -> ends at 15232
    unsigned int* done = (unsigned int*)(wsf + 15296);
    float2* wcent = (float2*)(wsf + 15304);       // [4*3840] float2, 8B aligned
    unsigned short* descb  = (unsigned short*)(wsf + 46080);   // 1KB-aligned
    unsigned short* wdescb = descb + (size_t)4 * MPAD * DD;

    hipLaunchKernelGGL(dl_prep_kernel, dim3(PREP_BLOCKS), dim3(256), 0, stream,
                       desc, wdesc, homog, mask, descb, wdescb, vm, vpart, wcent, done);
    hipLaunchKernelGGL(dl_gemm_loss_kernel, dim3(GB), dim3(256), 0, stream,
                       descb, wdescb, vm, wcent, vpart, gpart, done, out);
}